// Round 2
// baseline (359.420 us; speedup 1.0000x reference)
//
#include <hip/hip_runtime.h>

#define B_ 32
#define T_ 2048
#define H_ 256
#define L_ 2049   // T_ + 1

// ---------------- wave reduce helpers (wave = 64 lanes) ----------------
__device__ inline double waveReduceD(double v) {
#pragma unroll
  for (int off = 32; off > 0; off >>= 1) v += __shfl_xor(v, off, 64);
  return v;
}
__device__ inline float waveReduceF(float v) {
#pragma unroll
  for (int off = 32; off > 0; off >>= 1) v += __shfl_xor(v, off, 64);
  return v;
}

// ---------------- K0: fold the two linear layers ----------------
// v[c] = sum_o W2[o] * W1[o,c]   (c in [0,512))
// c0   = sum_o W2[o] * b1[o] + b2[0]
__global__ void __launch_bounds__(256) k0_fold(
    const float* __restrict__ W1, const float* __restrict__ b1,
    const float* __restrict__ W2, const float* __restrict__ b2,
    double* __restrict__ vd, double* __restrict__ c0) {
  int c = blockIdx.x * 256 + threadIdx.x;  // 0..511
  double acc = 0.0;
  for (int o = 0; o < 512; ++o) acc += (double)W2[o] * (double)W1[o * 512 + c];
  vd[c] = acc;
  if (blockIdx.x == 0) {
    __shared__ double red[256];
    double p = (double)W2[threadIdx.x] * (double)b1[threadIdx.x] +
               (double)W2[threadIdx.x + 256] * (double)b1[threadIdx.x + 256];
    red[threadIdx.x] = p;
    __syncthreads();
    for (int s = 128; s > 0; s >>= 1) {
      if (threadIdx.x < s) red[threadIdx.x] += red[threadIdx.x + s];
      __syncthreads();
    }
    if (threadIdx.x == 0) c0[0] = red[0] + (double)b2[0];
  }
}

// ---------------- K1: per-(b,t) row dots ----------------
// d1[r] = x_row . (v1+v2),  d2[r] = x_row . v2,  absS[r] = sum |x|
// one wave per row; 4 rows per 256-thread block
__global__ void __launch_bounds__(256) k1_rowdots(
    const float* __restrict__ x, const double* __restrict__ vd,
    double* __restrict__ d1, double* __restrict__ d2, float* __restrict__ absS) {
  int wave = threadIdx.x >> 6, lane = threadIdx.x & 63;
  long row = (long)blockIdx.x * 4 + wave;  // < B_*T_
  const float4* xr = (const float4*)(x + row * H_);
  float4 xa = xr[lane];
  int base = lane * 4;
  double va0 = vd[base + 0], va1 = vd[base + 1], va2 = vd[base + 2], va3 = vd[base + 3];
  double vb0 = vd[256 + base + 0], vb1 = vd[256 + base + 1],
         vb2 = vd[256 + base + 2], vb3 = vd[256 + base + 3];
  double p2 = (double)xa.x * vb0 + (double)xa.y * vb1 + (double)xa.z * vb2 + (double)xa.w * vb3;
  double p1 = (double)xa.x * (va0 + vb0) + (double)xa.y * (va1 + vb1) +
              (double)xa.z * (va2 + vb2) + (double)xa.w * (va3 + vb3);
  float pa = fabsf(xa.x) + fabsf(xa.y) + fabsf(xa.z) + fabsf(xa.w);
  p1 = waveReduceD(p1);
  p2 = waveReduceD(p2);
  pa = waveReduceF(pa);
  if (lane == 0) {
    d1[row] = p1;
    d2[row] = p2;
    absS[row] = pa;
  }
}

// ---------------- K2: weights, scaling, fire chain (one block per b) -----
__global__ void __launch_bounds__(256) k2_weights(
    const double* __restrict__ d1, const double* __restrict__ d2,
    const float* __restrict__ absS, const float* __restrict__ mask,
    const int* __restrict__ is_tr, const double* __restrict__ c0p,
    float* __restrict__ o_ori, float* __restrict__ o_sa, float* __restrict__ o_ff,
    float* __restrict__ wsc, int* __restrict__ fireT, int* __restrict__ outPos,
    int* __restrict__ nAllArr, int* __restrict__ nUnmArr) {
  __shared__ double s_w[T_];
  __shared__ double red[256];
  int b = blockIdx.x, tid = threadIdx.x;
  const double* d1b = d1 + (long)b * T_;
  const double* d2b = d2 + (long)b * T_;
  const float* asb = absS + (long)b * T_;
  double c0 = c0p[0];
  double sa = 0.0, fpc = 0.0;
  for (int t = tid; t < T_; t += 256) {
    double wv;
    if (t == 0) {
      wv = d1b[0] - d2b[0] + c0;  // hist[0] = x[0] -> hist.v2 = d2[0]
    } else {
      int start = t - 10;
      if (start < 0) start = 0;
      double hs = 0.0;
      for (int u = start; u < t; ++u) hs += d2b[u];
      wv = d1b[t] - hs / (double)(t - start) + c0;
    }
    // relu then clip at 1.0
    wv = wv < 0.0 ? 0.0 : (wv > 1.0 ? 1.0 : wv);
    o_ori[(long)b * T_ + t] = (float)wv;
    s_w[t] = wv;
    sa += wv;
    fpc += (asb[t] != 0.0f) ? 1.0 : 0.0;
  }
  red[tid] = sa; __syncthreads();
  for (int s = 128; s > 0; s >>= 1) { if (tid < s) red[tid] += red[tid + s]; __syncthreads(); }
  double sumA = red[0]; __syncthreads();
  red[tid] = fpc; __syncthreads();
  for (int s = 128; s > 0; s >>= 1) { if (tid < s) red[tid] += red[tid + s]; __syncthreads(); }
  double fpD = red[0]; __syncthreads();
  double ms = 0.0;
  for (int t = tid; t < 200; t += 256) ms += (double)mask[(long)b * 200 + t];
  red[tid] = ms; __syncthreads();
  for (int s = 128; s > 0; s >>= 1) { if (tid < s) red[tid] += red[tid + s]; __syncthreads(); }
  double maskSum = red[0]; __syncthreads();
  if (tid == 0) o_sa[b] = (float)sumA;
  int firstPad = (int)(fpD + 0.5);
  double scale;
  if (is_tr[0] != 0) {
    scale = (sumA == 0.0) ? 0.0 : (maskSum - 1.0) / (sumA > 1e-8 ? sumA : 1e-8);
  } else {
    scale = 1.0;
  }
  for (int t = tid; t < T_; t += 256) {
    double wv = s_w[t] * scale;
    if (t > firstPad) wv = 0.0;  // pad mask
    s_w[t] = wv;
    wsc[(long)b * T_ + t] = (float)wv;
  }
  __syncthreads();
  // ---- serial integrate-and-fire chain: whole wave 0, register-resident w.
  // All 64 lanes redundantly run the uniform chain; per 64-step block each
  // lane owns one w value (one coalesced ds_read) broadcast via readlane
  // (compile-time index), and lane i latches step i's fired flag so flag
  // stores are one coalesced 64-wide store per block instead of per-step.
  if (tid < 64) {
    int lane = tid;
    double prev = 0.0;
    int nA = 0, nU = 0;
    int* ftb = fireT + (long)b * T_;
    int* opb = outPos + (long)b * T_;
    float* ffb = o_ff + (long)b * T_;
    for (int blk = 0; blk < T_; blk += 64) {
      double wl = s_w[blk + lane];
      float myflag;
#pragma unroll
      for (int i = 0; i < 64; ++i) {
        double wv = __shfl(wl, i, 64);
        double nw = prev + wv;
        bool fired = nw > 1.0;
        if (i == lane) myflag = fired ? 1.0f : 0.0f;
        if (fired) {
          int t = blk + i;
          if (lane == 0) { ftb[nA] = t; opb[nA] = (t <= firstPad) ? nU : -1; }
          if (t <= firstPad) nU++;
          nA++;
        }
        prev = fired ? (nw - 1.0) : nw;
      }
      ffb[blk + lane] = myflag;
    }
    if (lane == 0) { nAllArr[b] = nA; nUnmArr[b] = nU; }
  }
}

// ---------------- K3: segment sums -> normalized cif rows ----------------
// one wave per fired row j in [0, nAll]; j == nAll is the final-state row.
// out_row = x[anchor] + sum_{u=lo..hi} (1-w[u]) * x[u]   (fp32, scan order)
__global__ void __launch_bounds__(64) k3_rows(
    const float* __restrict__ x, const float* __restrict__ wsc,
    const int* __restrict__ fireT, const int* __restrict__ outPos,
    const int* __restrict__ nAllArr, const int* __restrict__ nUnmArr,
    float* __restrict__ cif, float* __restrict__ notpad) {
  int j = blockIdx.x, b = blockIdx.y, lane = threadIdx.x;
  int nA = nAllArr[b];
  if (j > nA) return;
  const int* ftb = fireT + (long)b * T_;
  const int* opb = outPos + (long)b * T_;
  int hi, pos;
  if (j < nA) {
    hi = ftb[j];
    pos = opb[j];
    if (pos < 0) return;  // pad-masked fired row: zeroed & dropped
  } else {
    hi = T_ - 1;          // trailing state fin_s appended as last row
    pos = nUnmArr[b];
  }
  int lo, anchor;
  if (j == 0) { lo = 0; anchor = 0; }            // init state s = x[:,0,:]
  else { anchor = ftb[j - 1]; lo = anchor + 1; } // s reset to x[prev_fire]
  const float* xb = x + (long)b * T_ * H_;
  const float4* xav = (const float4*)(xb + (long)anchor * H_);
  float4 acc = xav[lane];
  const float* wb = wsc + (long)b * T_;
  for (int u = lo; u <= hi; ++u) {
    float f = 1.0f - wb[u];
    const float4* xu = (const float4*)(xb + (long)u * H_);
    float4 xv = xu[lane];
    acc.x += f * xv.x; acc.y += f * xv.y; acc.z += f * xv.z; acc.w += f * xv.w;
  }
  float ss = acc.x * acc.x + acc.y * acc.y + acc.z * acc.z + acc.w * acc.w;
  ss = waveReduceF(ss);
  float norm = sqrtf(ss);
  float inv = 1.0f / fmaxf(norm, 1e-12f);
  float4 o = make_float4(acc.x * inv, acc.y * inv, acc.z * inv, acc.w * inv);
  float4* crow = (float4*)(cif + ((long)b * L_ + pos) * H_);
  crow[lane] = o;
  if (lane == 0) notpad[(long)b * L_ + pos] = 1.0f;
}

// ---------------- launch ----------------
extern "C" void kernel_launch(void* const* d_in, const int* in_sizes, int n_in,
                              void* d_out, int out_size, void* d_ws, size_t ws_size,
                              hipStream_t stream) {
  const float* x    = (const float*)d_in[0];
  const float* mask = (const float*)d_in[1];
  const float* W1   = (const float*)d_in[2];
  const float* b1   = (const float*)d_in[3];
  const float* W2   = (const float*)d_in[4];
  const float* b2   = (const float*)d_in[5];
  const int*   istr = (const int*)d_in[6];

  float* out = (float*)d_out;
  // output layout (all fp32, concatenated in return order)
  float* o_cif = out;                                  // B*L*H
  float* o_ori = o_cif + (size_t)B_ * L_ * H_;         // B*T
  float* o_ff  = o_ori + (size_t)B_ * T_;              // B*T
  float* o_np  = o_ff  + (size_t)B_ * T_;              // B*L
  float* o_sa  = o_np  + (size_t)B_ * L_;              // B

  // workspace layout (~2.06 MB)
  char* w = (char*)d_ws;
  double* vd   = (double*)w; w += 512 * 8;
  double* c0   = (double*)w; w += 8;
  double* d1   = (double*)w; w += (size_t)B_ * T_ * 8;
  double* d2   = (double*)w; w += (size_t)B_ * T_ * 8;
  float* absS  = (float*)w;  w += (size_t)B_ * T_ * 4;
  float* wsc   = (float*)w;  w += (size_t)B_ * T_ * 4;
  int* fireT   = (int*)w;    w += (size_t)B_ * T_ * 4;
  int* outPos  = (int*)w;    w += (size_t)B_ * T_ * 4;
  int* nAllA   = (int*)w;    w += B_ * 4;
  int* nUnmA   = (int*)w;    w += B_ * 4;

  // zero outputs (cif is mostly zeros; notpad needs zeros)
  hipMemsetAsync(d_out, 0, (size_t)out_size * sizeof(float), stream);

  k0_fold<<<2, 256, 0, stream>>>(W1, b1, W2, b2, vd, c0);
  k1_rowdots<<<(B_ * T_) / 4, 256, 0, stream>>>(x, vd, d1, d2, absS);
  k2_weights<<<B_, 256, 0, stream>>>(d1, d2, absS, mask, istr, c0,
                                     o_ori, o_sa, o_ff, wsc, fireT, outPos,
                                     nAllA, nUnmA);
  k3_rows<<<dim3(L_, B_), 64, 0, stream>>>(x, wsc, fireT, outPos, nAllA, nUnmA,
                                           o_cif, o_np);
}

// Round 3
// 223.221 us; speedup vs baseline: 1.6101x; 1.6101x over previous
//
#include <hip/hip_runtime.h>

#define B_ 32
#define T_ 2048
#define H_ 256
#define L_ 2049   // T_ + 1
#define NBLK (T_ / 64)  // 32 chain blocks of 64 steps

// ---------------- wave reduce helpers (wave = 64 lanes) ----------------
__device__ inline double waveReduceD(double v) {
#pragma unroll
  for (int off = 32; off > 0; off >>= 1) v += __shfl_xor(v, off, 64);
  return v;
}

// ---------------- K0: fold the two linear layers ----------------
// v[c] = sum_o W2[o] * W1[o,c]   (c in [0,512)),  c0 = W2.b1 + b2
__global__ void __launch_bounds__(256) k0_fold(
    const float* __restrict__ W1, const float* __restrict__ b1,
    const float* __restrict__ W2, const float* __restrict__ b2,
    double* __restrict__ vd, double* __restrict__ c0) {
  int c = blockIdx.x * 256 + threadIdx.x;  // 0..511
  double acc = 0.0;
#pragma unroll 8
  for (int o = 0; o < 512; ++o) acc += (double)W2[o] * (double)W1[o * 512 + c];
  vd[c] = acc;
  if (blockIdx.x == 0) {
    __shared__ double red[256];
    double p = (double)W2[threadIdx.x] * (double)b1[threadIdx.x] +
               (double)W2[threadIdx.x + 256] * (double)b1[threadIdx.x + 256];
    red[threadIdx.x] = p;
    __syncthreads();
    for (int s = 128; s > 0; s >>= 1) {
      if (threadIdx.x < s) red[threadIdx.x] += red[threadIdx.x + s];
      __syncthreads();
    }
    if (threadIdx.x == 0) c0[0] = red[0] + (double)b2[0];
  }
}

// ---------------- K1: per-(b,t) row dots ----------------
// d1[r] = x_row.(v1+v2), d2[r] = x_row.v2, absS[r] = (any nonzero) ? 1 : 0
__global__ void __launch_bounds__(256) k1_rowdots(
    const float* __restrict__ x, const double* __restrict__ vd,
    double* __restrict__ d1, double* __restrict__ d2, float* __restrict__ absS) {
  int wave = threadIdx.x >> 6, lane = threadIdx.x & 63;
  long row = (long)blockIdx.x * 4 + wave;  // < B_*T_
  const float4* xr = (const float4*)(x + row * H_);
  float4 xa = xr[lane];
  int base = lane * 4;
  double va0 = vd[base + 0], va1 = vd[base + 1], va2 = vd[base + 2], va3 = vd[base + 3];
  double vb0 = vd[256 + base + 0], vb1 = vd[256 + base + 1],
         vb2 = vd[256 + base + 2], vb3 = vd[256 + base + 3];
  double p2 = (double)xa.x * vb0 + (double)xa.y * vb1 + (double)xa.z * vb2 + (double)xa.w * vb3;
  double p1 = (double)xa.x * (va0 + vb0) + (double)xa.y * (va1 + vb1) +
              (double)xa.z * (va2 + vb2) + (double)xa.w * (va3 + vb3);
  bool nz = (xa.x != 0.0f) || (xa.y != 0.0f) || (xa.z != 0.0f) || (xa.w != 0.0f);
  unsigned long long bal = __ballot(nz);
  p1 = waveReduceD(p1);
  p2 = waveReduceD(p2);
  if (lane == 0) {
    d1[row] = p1;
    d2[row] = p2;
    absS[row] = bal ? 1.0f : 0.0f;
  }
}

// ---------------- K2: weights, scaling, fire chain (one block per b) -----
__global__ void __launch_bounds__(256) k2_weights(
    const double* __restrict__ d1, const double* __restrict__ d2,
    const float* __restrict__ absS, const float* __restrict__ mask,
    const int* __restrict__ is_tr, const double* __restrict__ c0p,
    float* __restrict__ o_ori, float* __restrict__ o_sa, float* __restrict__ o_ff,
    float* __restrict__ wsc, int* __restrict__ fireT, int* __restrict__ outPos,
    int* __restrict__ nAllArr, int* __restrict__ nUnmArr) {
  __shared__ double s_d2[T_];                   // 16 KB
  __shared__ float s_wf[T_];                    // 8 KB (scaled+masked w)
  __shared__ double red[256];                   // 2 KB
  __shared__ unsigned long long s_mask[NBLK];   // fired bitmasks
  __shared__ int s_ppc[NBLK];                   // exclusive prefix popcounts
  int b = blockIdx.x, tid = threadIdx.x;
  const double* d1b = d1 + (long)b * T_;
  const double* d2b = d2 + (long)b * T_;
  const float* asb = absS + (long)b * T_;
  double c0 = c0p[0];

  // stage d2 into LDS (coalesced) for the window sums
  for (int i = tid; i < T_; i += 256) s_d2[i] = d2b[i];
  __syncthreads();

  // ---- Part A: w = clip(relu(d1 - windowmean(d2) + c0), 0, 1)
  float wloc[8];
  double sa = 0.0, fpc = 0.0;
#pragma unroll
  for (int k = 0; k < 8; ++k) {
    int t = tid + k * 256;
    double wv;
    if (t == 0) {
      wv = d1b[0] - s_d2[0] + c0;  // hist[0] = x[0]
    } else if (t < 10) {
      double hs = 0.0;
      for (int u = 0; u < t; ++u) hs += s_d2[u];
      wv = d1b[t] - hs / (double)t + c0;
    } else {
      double hs = 0.0;
#pragma unroll
      for (int u = 1; u <= 10; ++u) hs += s_d2[t - u];
      wv = d1b[t] - hs / 10.0 + c0;
    }
    wv = wv < 0.0 ? 0.0 : (wv > 1.0 ? 1.0 : wv);
    float wf = (float)wv;
    wloc[k] = wf;
    o_ori[(long)b * T_ + t] = wf;
    sa += (double)wf;
    fpc += (asb[t] != 0.0f) ? 1.0 : 0.0;
  }
  // reductions: sum_a, first_pad count, mask sum
  red[tid] = sa; __syncthreads();
  for (int s = 128; s > 0; s >>= 1) { if (tid < s) red[tid] += red[tid + s]; __syncthreads(); }
  double sumA = red[0]; __syncthreads();
  red[tid] = fpc; __syncthreads();
  for (int s = 128; s > 0; s >>= 1) { if (tid < s) red[tid] += red[tid + s]; __syncthreads(); }
  double fpD = red[0]; __syncthreads();
  double ms = 0.0;
  for (int t = tid; t < 200; t += 256) ms += (double)mask[(long)b * 200 + t];
  red[tid] = ms; __syncthreads();
  for (int s = 128; s > 0; s >>= 1) { if (tid < s) red[tid] += red[tid + s]; __syncthreads(); }
  double maskSum = red[0]; __syncthreads();
  if (tid == 0) o_sa[b] = (float)sumA;
  int firstPad = (int)(fpD + 0.5);
  double scale;
  if (is_tr[0] != 0) {
    scale = (sumA == 0.0) ? 0.0 : (maskSum - 1.0) / (sumA > 1e-8 ? sumA : 1e-8);
  } else {
    scale = 1.0;
  }
  float scalef = (float)scale;
  // scaled + pad-masked w -> LDS + global (for k3)
#pragma unroll
  for (int k = 0; k < 8; ++k) {
    int t = tid + k * 256;
    float wv = wloc[k] * scalef;
    if (t > firstPad) wv = 0.0f;
    s_wf[t] = wv;
    wsc[(long)b * T_ + t] = wv;
  }
  __syncthreads();

  // ---- Part B: serial fire chain, wave 0 only, register-resident w.
  // All 64 lanes redundantly run the chain; w values arrive via same-address
  // LDS float4 reads (broadcast, conflict-free), double-buffered so the
  // dependent chain never waits on memory. Lane i latches step i's flag;
  // one __ballot per 64 steps -> bitmask in LDS.
  if (tid < 64) {
    int lane = tid;
    const float4* sw4 = (const float4*)s_wf;
    float4 cur[16], nxt[16];
#pragma unroll
    for (int k = 0; k < 16; ++k) cur[k] = sw4[k];
    float prev = 0.0f;
    for (int blk = 0; blk < NBLK; ++blk) {
      if (blk + 1 < NBLK) {
#pragma unroll
        for (int k = 0; k < 16; ++k) nxt[k] = sw4[(blk + 1) * 16 + k];
      }
      bool myf = false;
#pragma unroll
      for (int k = 0; k < 16; ++k) {
#define STEP(COMP, IDX)                                   \
        {                                                 \
          float wv = cur[k].COMP;                         \
          float nw = prev + wv;                           \
          bool fired = nw > 1.0f;                         \
          float fw = wv - (1.0f - prev);                  \
          if ((4 * k + IDX) == lane) myf = fired;         \
          prev = fired ? fw : nw;                         \
        }
        STEP(x, 0) STEP(y, 1) STEP(z, 2) STEP(w, 3)
#undef STEP
      }
      unsigned long long bal = __ballot(myf);
      if (lane == 0) s_mask[blk] = bal;
#pragma unroll
      for (int k = 0; k < 16; ++k) cur[k] = nxt[k];
    }
  }
  __syncthreads();

  // ---- compaction bookkeeping (tiny serial prefix)
  if (tid == 0) {
    int run = 0;
    for (int k = 0; k < NBLK; ++k) { s_ppc[k] = run; run += __popcll(s_mask[k]); }
    int nA = run;
    int nU;
    if (firstPad >= T_ - 1) {
      nU = nA;
    } else {
      int fb = firstPad >> 6, bit = firstPad & 63;
      unsigned long long keep =
          (bit == 63) ? ~0ull : ((1ull << (bit + 1)) - 1ull);
      nU = s_ppc[fb] + __popcll(s_mask[fb] & keep);
    }
    nAllArr[b] = nA;
    nUnmArr[b] = nU;
  }
  __syncthreads();

  // ---- parallel flag write + fire-list construction
  // fires with t <= firstPad are a prefix of the fire list, so their
  // unmasked index equals their rank.
#pragma unroll
  for (int k = 0; k < 8; ++k) {
    int t = tid + k * 256;
    int blkI = t >> 6, bit = t & 63;
    unsigned long long m = s_mask[blkI];
    bool f = (m >> bit) & 1ull;
    o_ff[(long)b * T_ + t] = f ? 1.0f : 0.0f;
    if (f) {
      int rank = s_ppc[blkI] + __popcll(m & ((1ull << bit) - 1ull));
      fireT[(long)b * T_ + rank] = t;
      outPos[(long)b * T_ + rank] = (t <= firstPad) ? rank : -1;
    }
  }
}

// ---------------- K3: segment sums -> normalized cif rows ----------------
// one wave per fired row j in [0, nAll]; j == nAll is the final-state row.
// out_row = x[anchor] + sum_{u=lo..hi} (1-w[u]) * x[u]   (fp32, scan order)
#define MAXR_ 512  // fire count per b is ~mask_sum-1 (~199) << 512
__global__ void __launch_bounds__(64) k3_rows(
    const float* __restrict__ x, const float* __restrict__ wsc,
    const int* __restrict__ fireT, const int* __restrict__ outPos,
    const int* __restrict__ nAllArr, const int* __restrict__ nUnmArr,
    float* __restrict__ cif, float* __restrict__ notpad) {
  int j = blockIdx.x, b = blockIdx.y, lane = threadIdx.x;
  int nA = nAllArr[b];
  if (j > nA) return;
  const int* ftb = fireT + (long)b * T_;
  const int* opb = outPos + (long)b * T_;
  int hi, pos;
  if (j < nA) {
    hi = ftb[j];
    pos = opb[j];
    if (pos < 0) return;  // pad-masked fired row: zeroed & dropped
  } else {
    hi = T_ - 1;          // trailing state fin_s appended as last row
    pos = nUnmArr[b];
  }
  int lo, anchor;
  if (j == 0) { lo = 0; anchor = 0; }            // init state s = x[:,0,:]
  else { anchor = ftb[j - 1]; lo = anchor + 1; } // s reset to x[prev_fire]
  const float* xb = x + (long)b * T_ * H_;
  const float4* xav = (const float4*)(xb + (long)anchor * H_);
  float4 acc = xav[lane];
  const float* wb = wsc + (long)b * T_;
  for (int u = lo; u <= hi; ++u) {
    float f = 1.0f - wb[u];
    const float4* xu = (const float4*)(xb + (long)u * H_);
    float4 xv = xu[lane];
    acc.x += f * xv.x; acc.y += f * xv.y; acc.z += f * xv.z; acc.w += f * xv.w;
  }
  float ss = acc.x * acc.x + acc.y * acc.y + acc.z * acc.z + acc.w * acc.w;
#pragma unroll
  for (int off = 32; off > 0; off >>= 1) ss += __shfl_xor(ss, off, 64);
  float norm = sqrtf(ss);
  float inv = 1.0f / fmaxf(norm, 1e-12f);
  float4 o = make_float4(acc.x * inv, acc.y * inv, acc.z * inv, acc.w * inv);
  float4* crow = (float4*)(cif + ((long)b * L_ + pos) * H_);
  crow[lane] = o;
  if (lane == 0) notpad[(long)b * L_ + pos] = 1.0f;
}

// ---------------- launch ----------------
extern "C" void kernel_launch(void* const* d_in, const int* in_sizes, int n_in,
                              void* d_out, int out_size, void* d_ws, size_t ws_size,
                              hipStream_t stream) {
  const float* x    = (const float*)d_in[0];
  const float* mask = (const float*)d_in[1];
  const float* W1   = (const float*)d_in[2];
  const float* b1   = (const float*)d_in[3];
  const float* W2   = (const float*)d_in[4];
  const float* b2   = (const float*)d_in[5];
  const int*   istr = (const int*)d_in[6];

  float* out = (float*)d_out;
  // output layout (all fp32, concatenated in return order)
  float* o_cif = out;                                  // B*L*H
  float* o_ori = o_cif + (size_t)B_ * L_ * H_;         // B*T
  float* o_ff  = o_ori + (size_t)B_ * T_;              // B*T
  float* o_np  = o_ff  + (size_t)B_ * T_;              // B*L
  float* o_sa  = o_np  + (size_t)B_ * L_;              // B

  // workspace layout (~2.06 MB)
  char* w = (char*)d_ws;
  double* vd   = (double*)w; w += 512 * 8;
  double* c0   = (double*)w; w += 8;
  double* d1   = (double*)w; w += (size_t)B_ * T_ * 8;
  double* d2   = (double*)w; w += (size_t)B_ * T_ * 8;
  float* absS  = (float*)w;  w += (size_t)B_ * T_ * 4;
  float* wsc   = (float*)w;  w += (size_t)B_ * T_ * 4;
  int* fireT   = (int*)w;    w += (size_t)B_ * T_ * 4;
  int* outPos  = (int*)w;    w += (size_t)B_ * T_ * 4;
  int* nAllA   = (int*)w;    w += B_ * 4;
  int* nUnmA   = (int*)w;    w += B_ * 4;

  // zero outputs (cif is mostly zeros; notpad needs zeros)
  hipMemsetAsync(d_out, 0, (size_t)out_size * sizeof(float), stream);

  k0_fold<<<2, 256, 0, stream>>>(W1, b1, W2, b2, vd, c0);
  k1_rowdots<<<(B_ * T_) / 4, 256, 0, stream>>>(x, vd, d1, d2, absS);
  k2_weights<<<B_, 256, 0, stream>>>(d1, d2, absS, mask, istr, c0,
                                     o_ori, o_sa, o_ff, wsc, fireT, outPos,
                                     nAllA, nUnmA);
  k3_rows<<<dim3(MAXR_, B_), 64, 0, stream>>>(x, wsc, fireT, outPos, nAllA, nUnmA,
                                              o_cif, o_np);
}